// Round 10
// baseline (368.384 us; speedup 1.0000x reference)
//
#include <hip/hip_runtime.h>
#include <hip/hip_bf16.h>
#include <hip/hip_cooperative_groups.h>

namespace cg = cooperative_groups;

// Sizes fixed by the reference problem.
#define B_N   4096
#define D_N   1024
#define P_N   64
#define C0_N  16
#define C1_N  32
#define NC_N  48    // C0 + C1 concatenated

// Fused-kernel geometry: 512 blocks x 256 threads, 2 blocks/CU co-resident.
#define FKC   8      // K-chunks (both GEMM phases)
#define FDK   128    // chunk depth
#define FLS   132    // LDS row stride (floats)
#define FGRID 512

// Tie physics: fp32 softmax probs can only tie when the true logit gap is
// <~2e-7 (exp ulp 6e-8 near 1.0; prob ulp 1.9e-9 x s~64 = 1.2e-7; exp
// rounding +-6e-8). Our fp32 gap estimate is accurate to ~1e-9. tau=1e-6
// gives 5x margin and flags only ~15-30 rows.
#define GAP_TAU 1e-6f
#define NEG_INF (-3.402823466e38f)

// ===========================================================================
// FUSED cooperative kernel: all 4 phases, 3 grid.sync()s, zero launch gaps.
// P1 parent partials -> P2 route(+inline f64 fixup) -> P3 child partials
// -> P4 child reduce. Partials layouts: [row][kc][p] and [row][kc][j]
// (row-contiguous blocks for the reducers).
// ===========================================================================
__global__ __launch_bounds__(256, 2)
void hc_fused(const float* __restrict__ x,  const float* __restrict__ pw,
              const float* __restrict__ pb, const float* __restrict__ w0,
              const float* __restrict__ b0, const float* __restrict__ w1,
              const float* __restrict__ b1,
              float* __restrict__ out_logits, float* __restrict__ out_c0,
              float* __restrict__ out_c1,
              int* counts, int* pclass, int* lists,
              float* partials, float* part2) {
    cg::grid_group grid = cg::this_grid();

    __shared__ float  xs[64 * FLS];
    __shared__ float  ws[64 * FLS];
    __shared__ int    rl[64];
    __shared__ double ld[P_N];
    __shared__ int    sq[8];
    __shared__ int    sqn;

    const int tid = threadIdx.x;
    const int bx  = blockIdx.x;

    // ------------------------- phase 1: parent partials -------------------
    {
        if (bx == 0 && tid < P_N) counts[tid] = 0;

        const int r0 = (bx >> 3) * 64;   // 64 row-tiles
        const int kc = bx & 7;           // 8 K-chunks
        const int d0 = kc * FDK;

        #pragma unroll
        for (int k = 0; k < 8; ++k) {    // x: 64 rows x 128 floats
            const int f  = tid + 256 * k;
            const int r  = f >> 5;
            const int dp = (f & 31) * 4;
            *(float4*)&xs[r * FLS + dp] =
                *(const float4*)&x[(size_t)(r0 + r) * D_N + d0 + dp];
        }
        #pragma unroll
        for (int k = 0; k < 8; ++k) {    // pw chunk: 64 rows x 128 floats
            const int f  = tid + 256 * k;
            const int r  = f >> 5;
            const int dp = (f & 31) * 4;
            *(float4*)&ws[r * FLS + dp] =
                *(const float4*)&pw[(size_t)r * D_N + d0 + dp];
        }
        __syncthreads();

        const int pt = tid & 15;
        const int rt = tid >> 4;

        float acc[4][4] = {};            // [i: parent][j: row]
        #pragma unroll 2
        for (int d = 0; d < FDK; d += 4) {
            float4 w4[4], x4[4];
            #pragma unroll
            for (int i = 0; i < 4; ++i)
                w4[i] = *(const float4*)&ws[(pt + 16 * i) * FLS + d];
            #pragma unroll
            for (int j = 0; j < 4; ++j)
                x4[j] = *(const float4*)&xs[(rt * 4 + j) * FLS + d];
            #pragma unroll
            for (int i = 0; i < 4; ++i)
                #pragma unroll
                for (int j = 0; j < 4; ++j) {
                    acc[i][j] += w4[i].x * x4[j].x;
                    acc[i][j] += w4[i].y * x4[j].y;
                    acc[i][j] += w4[i].z * x4[j].z;
                    acc[i][j] += w4[i].w * x4[j].w;
                }
        }

        #pragma unroll
        for (int j = 0; j < 4; ++j) {
            const size_t rbase =
                (size_t)(r0 + rt * 4 + j) * (FKC * P_N) + (size_t)kc * P_N;
            #pragma unroll
            for (int i = 0; i < 4; ++i)
                partials[rbase + pt + 16 * i] = acc[i][j];
        }
    }
    __threadfence();
    grid.sync();

    // ---------------- phase 2: route + inline block-level fixup -----------
    {
        if (tid == 0) sqn = 0;
        __syncthreads();

        const int p = tid & 63;
        const int w = tid >> 6;

        #pragma unroll
        for (int r2 = 0; r2 < 2; ++r2) {
            const int row = bx * 8 + w * 2 + r2;
            const float* prow = &partials[(size_t)row * (FKC * P_N)];
            float lv[FKC];
            #pragma unroll
            for (int kc = 0; kc < FKC; ++kc)
                lv[kc] = prow[kc * P_N + p];
            float l = pb[p];
            #pragma unroll
            for (int kc = 0; kc < FKC; ++kc)
                l += lv[kc];

            out_logits[(size_t)row * P_N + p] = l;

            // top-2 across the wave, first-max tiebreak
            float m1 = l;
            int   i1 = p;
            float m2 = NEG_INF;
            #pragma unroll
            for (int off = 32; off > 0; off >>= 1) {
                const float om1 = __shfl_xor(m1, off);
                const int   oi1 = __shfl_xor(i1, off);
                const float om2 = __shfl_xor(m2, off);
                if (om1 > m1 || (om1 == m1 && oi1 < i1)) {
                    m2 = fmaxf(m1, om2);
                    m1 = om1;
                    i1 = oi1;
                } else {
                    m2 = fmaxf(m2, om1);
                }
            }
            if (p == 0) {
                if (m1 - m2 > GAP_TAU) {
                    const int pos = atomicAdd(&counts[i1], 1);
                    lists[i1 * B_N + pos] = row;
                    pclass[row] = i1;
                } else {
                    const int q = atomicAdd(&sqn, 1);
                    sq[q] = row;
                }
            }
        }
        __syncthreads();

        // block-level f64 fixup for this block's suspects (usually none):
        // emulate the reference's fp32 softmax (exp quantization near 1.0
        // ties near-equal logits; argmax picks the FIRST tied index).
        const int nq   = sqn;
        const int lane = tid & 63;
        for (int qi = 0; qi < nq; ++qi) {
            const int row = sq[qi];
            const float* xr = &x[(size_t)row * D_N + lane * 16];
            float4 xv[4];
            #pragma unroll
            for (int k = 0; k < 4; ++k)
                xv[k] = *(const float4*)&xr[k * 4];

            #pragma unroll 2
            for (int pass = 0; pass < 16; ++pass) {
                const int pp = w * 16 + pass;
                const float* wr = &pw[(size_t)pp * D_N + lane * 16];
                double a0 = 0.0, a1 = 0.0, a2 = 0.0, a3 = 0.0;
                #pragma unroll
                for (int k = 0; k < 4; ++k) {
                    const float4 wv = *(const float4*)&wr[k * 4];
                    a0 = fma((double)wv.x, (double)xv[k].x, a0);
                    a1 = fma((double)wv.y, (double)xv[k].y, a1);
                    a2 = fma((double)wv.z, (double)xv[k].z, a2);
                    a3 = fma((double)wv.w, (double)xv[k].w, a3);
                }
                double a = (a0 + a1) + (a2 + a3);
                #pragma unroll
                for (int off = 32; off > 0; off >>= 1)
                    a += __shfl_xor(a, off);
                if (lane == 0) ld[pp] = a;
            }
            __syncthreads();

            if (w == 0) {
                const double accv = (double)pb[lane] + ld[lane];
                const float  l32  = (float)accv;
                float m = l32;
                #pragma unroll
                for (int off = 32; off > 0; off >>= 1)
                    m = fmaxf(m, __shfl_xor(m, off));
                const float e = (float)exp((double)(l32 - m));
                double es = (double)e;
                #pragma unroll
                for (int off = 32; off > 0; off >>= 1)
                    es += __shfl_xor(es, off);
                es = __shfl(es, 0);
                const float s    = (float)es;
                const float prob = e / s;     // IEEE f32 divide: ties survive
                float pm = prob;
                int   pi = lane;
                #pragma unroll
                for (int off = 32; off > 0; off >>= 1) {
                    const float opm = __shfl_xor(pm, off);
                    const int   opi = __shfl_xor(pi, off);
                    if (opm > pm || (opm == pm && opi < pi)) { pm = opm; pi = opi; }
                }
                if (lane == 0) {
                    const int pos = atomicAdd(&counts[pi], 1);
                    lists[pi * B_N + pos] = row;
                    pclass[row] = pi;
                }
            }
            __syncthreads();
        }
    }
    __threadfence();
    grid.sync();

    // ------------------------- phase 3: child partials --------------------
    {
        const int c  = bx >> 3;
        const int kc = bx & 7;
        const int d0 = kc * FDK;
        const int n  = counts[c];

        #pragma unroll
        for (int k = 0; k < 6; ++k) {    // 48 weight rows x 128 floats
            const int f  = tid + 256 * k;
            const int j  = f >> 5;
            const int dp = (f & 31) * 4;
            const float* src = (j < C0_N)
                ? &w0[((size_t)c * C0_N + j) * D_N + d0 + dp]
                : &w1[((size_t)c * C1_N + (j - C0_N)) * D_N + d0 + dp];
            *(float4*)&ws[j * FLS + dp] = *(const float4*)src;
        }

        const int jt = tid & 15;
        const int rt = tid >> 4;

        for (int t0 = 0; t0 < n; t0 += 64) {
            const int m = min(64, n - t0);
            __syncthreads();
            if (tid < 64)
                rl[tid] = lists[c * B_N + t0 + (tid < m ? tid : 0)];
            __syncthreads();
            #pragma unroll
            for (int k = 0; k < 8; ++k) {
                const int f  = tid + 256 * k;
                const int r  = f >> 5;
                const int dp = (f & 31) * 4;
                *(float4*)&xs[r * FLS + dp] =
                    *(const float4*)&x[(size_t)rl[r] * D_N + d0 + dp];
            }
            __syncthreads();

            float acc[3][4] = {};        // [i: output][j: row]
            #pragma unroll 2
            for (int d = 0; d < FDK; d += 4) {
                float4 w4[3], x4[4];
                #pragma unroll
                for (int i = 0; i < 3; ++i)
                    w4[i] = *(const float4*)&ws[(jt + 16 * i) * FLS + d];
                #pragma unroll
                for (int j = 0; j < 4; ++j)
                    x4[j] = *(const float4*)&xs[(rt * 4 + j) * FLS + d];
                #pragma unroll
                for (int i = 0; i < 3; ++i)
                    #pragma unroll
                    for (int j = 0; j < 4; ++j) {
                        acc[i][j] += w4[i].x * x4[j].x;
                        acc[i][j] += w4[i].y * x4[j].y;
                        acc[i][j] += w4[i].z * x4[j].z;
                        acc[i][j] += w4[i].w * x4[j].w;
                    }
            }

            #pragma unroll
            for (int j = 0; j < 4; ++j) {
                const int rr = rt * 4 + j;
                if (rr < m) {
                    const size_t rbase =
                        (size_t)rl[rr] * (FKC * NC_N) + (size_t)kc * NC_N;
                    #pragma unroll
                    for (int i = 0; i < 3; ++i)
                        part2[rbase + jt + 16 * i] = acc[i][j];
                }
            }
        }
    }
    __threadfence();
    grid.sync();

    // ------------------------- phase 4: child reduce ----------------------
    {
        for (int t = bx * 256 + tid; t < B_N * NC_N; t += FGRID * 256) {
            const int row = t / NC_N;
            const int j   = t - row * NC_N;
            const float* prow = &part2[(size_t)row * (FKC * NC_N)];
            float lv[FKC];
            #pragma unroll
            for (int kc = 0; kc < FKC; ++kc)
                lv[kc] = prow[kc * NC_N + j];
            float v = 0.f;
            #pragma unroll
            for (int kc = 0; kc < FKC; ++kc)
                v += lv[kc];
            const int c = pclass[row];
            if (j < C0_N)
                out_c0[(size_t)row * C0_N + j] = v + b0[c * C0_N + j];
            else
                out_c1[(size_t)row * C1_N + (j - C0_N)] =
                    v + b1[c * C1_N + (j - C0_N)];
        }
    }
}

// ===========================================================================
// FALLBACK: r9's proven 5-kernel chain (used only if cooperative launch is
// rejected, e.g. by graph capture). Constants suffixed to avoid collisions.
// ===========================================================================
#define KC1   16
#define DKC1  64
#define L1S   68
#define KC2   8
#define DKC2  128
#define L2S   132

__global__ __launch_bounds__(256, 4)
void hc_parent_partial(const float* __restrict__ x,
                       const float* __restrict__ pw,
                       float* __restrict__ partials,
                       int* __restrict__ counts,
                       int* __restrict__ nsus) {
    __shared__ float xs[64 * L1S];
    __shared__ float ws[P_N * L1S];
    const int tid = threadIdx.x;
    if (blockIdx.x == 0 && blockIdx.y == 0 && tid <= P_N) {
        if (tid < P_N) counts[tid] = 0;
        else           *nsus = 0;
    }
    const int r0 = blockIdx.x * 64;
    const int d0 = blockIdx.y * DKC1;
    #pragma unroll
    for (int k = 0; k < 4; ++k) {
        const int f = tid + 256 * k, r = f >> 4, dp = (f & 15) * 4;
        *(float4*)&xs[r * L1S + dp] =
            *(const float4*)&x[(size_t)(r0 + r) * D_N + d0 + dp];
    }
    #pragma unroll
    for (int k = 0; k < 4; ++k) {
        const int f = tid + 256 * k, r = f >> 4, dp = (f & 15) * 4;
        *(float4*)&ws[r * L1S + dp] =
            *(const float4*)&pw[(size_t)r * D_N + d0 + dp];
    }
    __syncthreads();
    const int pt = tid & 15, rt = tid >> 4;
    float acc[4][4] = {};
    #pragma unroll
    for (int d = 0; d < DKC1; d += 4) {
        float4 w4[4], x4[4];
        #pragma unroll
        for (int i = 0; i < 4; ++i)
            w4[i] = *(const float4*)&ws[(pt + 16 * i) * L1S + d];
        #pragma unroll
        for (int j = 0; j < 4; ++j)
            x4[j] = *(const float4*)&xs[(rt + 16 * j) * L1S + d];
        #pragma unroll
        for (int i = 0; i < 4; ++i)
            #pragma unroll
            for (int j = 0; j < 4; ++j) {
                acc[i][j] += w4[i].x * x4[j].x;
                acc[i][j] += w4[i].y * x4[j].y;
                acc[i][j] += w4[i].z * x4[j].z;
                acc[i][j] += w4[i].w * x4[j].w;
            }
    }
    const int kcb = blockIdx.y;
    #pragma unroll
    for (int j = 0; j < 4; ++j) {
        const size_t rbase =
            (size_t)(r0 + rt + 16 * j) * (KC1 * P_N) + (size_t)kcb * P_N;
        #pragma unroll
        for (int i = 0; i < 4; ++i)
            partials[rbase + pt + 16 * i] = acc[i][j];
    }
}

__global__ __launch_bounds__(256)
void hc_parent_route(const float* __restrict__ partials,
                     const float* __restrict__ pb,
                     float* __restrict__ out_logits,
                     int* __restrict__ counts,
                     int* __restrict__ lists,
                     int* __restrict__ nsus,
                     int* __restrict__ suspects,
                     int* __restrict__ pclass) {
    const int tid = threadIdx.x;
    const int p = tid & 63, w = tid >> 6;
    const int row = blockIdx.x * 4 + w;
    const float* prow = &partials[(size_t)row * (KC1 * P_N)];
    float lv[KC1];
    #pragma unroll
    for (int kc = 0; kc < KC1; ++kc) lv[kc] = prow[kc * P_N + p];
    float l = pb[p];
    #pragma unroll
    for (int kc = 0; kc < KC1; ++kc) l += lv[kc];
    out_logits[(size_t)row * P_N + p] = l;
    float m1 = l; int i1 = p; float m2 = NEG_INF;
    #pragma unroll
    for (int off = 32; off > 0; off >>= 1) {
        const float om1 = __shfl_xor(m1, off);
        const int   oi1 = __shfl_xor(i1, off);
        const float om2 = __shfl_xor(m2, off);
        if (om1 > m1 || (om1 == m1 && oi1 < i1)) {
            m2 = fmaxf(m1, om2); m1 = om1; i1 = oi1;
        } else m2 = fmaxf(m2, om1);
    }
    if (p == 0) {
        if (m1 - m2 > GAP_TAU) {
            const int pos = atomicAdd(&counts[i1], 1);
            lists[i1 * B_N + pos] = row;
            pclass[row] = i1;
        } else {
            const int pos = atomicAdd(nsus, 1);
            suspects[pos] = row;
        }
    }
}

__global__ __launch_bounds__(256)
void hc_fixup(const float* __restrict__ x, const float* __restrict__ pw,
              const float* __restrict__ pb, const int* __restrict__ nsus,
              const int* __restrict__ suspects, int* __restrict__ counts,
              int* __restrict__ lists, int* __restrict__ pclass) {
    __shared__ double ld[P_N];
    const int tid = threadIdx.x, lane = tid & 63, w = tid >> 6;
    const int ns = *nsus;
    for (int sidx = blockIdx.x; sidx < ns; sidx += gridDim.x) {
        const int row = suspects[sidx];
        __syncthreads();
        const float* xr = &x[(size_t)row * D_N + lane * 16];
        float4 xv[4];
        #pragma unroll
        for (int k = 0; k < 4; ++k) xv[k] = *(const float4*)&xr[k * 4];
        #pragma unroll 2
        for (int pass = 0; pass < 16; ++pass) {
            const int pp = w * 16 + pass;
            const float* wr = &pw[(size_t)pp * D_N + lane * 16];
            double a0 = 0.0, a1 = 0.0, a2 = 0.0, a3 = 0.0;
            #pragma unroll
            for (int k = 0; k < 4; ++k) {
                const float4 wv = *(const float4*)&wr[k * 4];
                a0 = fma((double)wv.x, (double)xv[k].x, a0);
                a1 = fma((double)wv.y, (double)xv[k].y, a1);
                a2 = fma((double)wv.z, (double)xv[k].z, a2);
                a3 = fma((double)wv.w, (double)xv[k].w, a3);
            }
            double a = (a0 + a1) + (a2 + a3);
            #pragma unroll
            for (int off = 32; off > 0; off >>= 1) a += __shfl_xor(a, off);
            if (lane == 0) ld[pp] = a;
        }
        __syncthreads();
        if (w == 0) {
            const double acc = (double)pb[lane] + ld[lane];
            const float l32 = (float)acc;
            float m = l32;
            #pragma unroll
            for (int off = 32; off > 0; off >>= 1)
                m = fmaxf(m, __shfl_xor(m, off));
            const float e = (float)exp((double)(l32 - m));
            double es = (double)e;
            #pragma unroll
            for (int off = 32; off > 0; off >>= 1) es += __shfl_xor(es, off);
            es = __shfl(es, 0);
            const float s = (float)es;
            const float prob = e / s;
            float pm = prob; int pi = lane;
            #pragma unroll
            for (int off = 32; off > 0; off >>= 1) {
                const float opm = __shfl_xor(pm, off);
                const int   opi = __shfl_xor(pi, off);
                if (opm > pm || (opm == pm && opi < pi)) { pm = opm; pi = opi; }
            }
            if (lane == 0) {
                const int pos = atomicAdd(&counts[pi], 1);
                lists[pi * B_N + pos] = row;
                pclass[row] = pi;
            }
        }
    }
}

__global__ __launch_bounds__(256, 2)
void hc_child_partial(const float* __restrict__ x, const float* __restrict__ w0,
                      const float* __restrict__ w1, const int* __restrict__ counts,
                      const int* __restrict__ lists, float* __restrict__ part2) {
    const int c = blockIdx.x, kc = blockIdx.y;
    const int n = counts[c];
    const int d0 = kc * DKC2;
    __shared__ int   rl[64];
    __shared__ float xs[64 * L2S];
    __shared__ float ws[NC_N * L2S];
    const int tid = threadIdx.x;
    #pragma unroll
    for (int k = 0; k < 6; ++k) {
        const int f = tid + 256 * k, j = f >> 5, dp = (f & 31) * 4;
        const float* src = (j < C0_N)
            ? &w0[((size_t)c * C0_N + j) * D_N + d0 + dp]
            : &w1[((size_t)c * C1_N + (j - C0_N)) * D_N + d0 + dp];
        *(float4*)&ws[j * L2S + dp] = *(const float4*)src;
    }
    const int jt = tid & 15, rt = tid >> 4;
    for (int t0 = 0; t0 < n; t0 += 64) {
        const int m = min(64, n - t0);
        __syncthreads();
        if (tid < 64) rl[tid] = lists[c * B_N + t0 + (tid < m ? tid : 0)];
        __syncthreads();
        #pragma unroll
        for (int k = 0; k < 8; ++k) {
            const int f = tid + 256 * k, r = f >> 5, dp = (f & 31) * 4;
            *(float4*)&xs[r * L2S + dp] =
                *(const float4*)&x[(size_t)rl[r] * D_N + d0 + dp];
        }
        __syncthreads();
        float acc[3][4] = {};
        #pragma unroll 2
        for (int d = 0; d < DKC2; d += 4) {
            float4 w4[3], x4[4];
            #pragma unroll
            for (int i = 0; i < 3; ++i)
                w4[i] = *(const float4*)&ws[(jt + 16 * i) * L2S + d];
            #pragma unroll
            for (int j = 0; j < 4; ++j)
                x4[j] = *(const float4*)&xs[(rt + 16 * j) * L2S + d];
            #pragma unroll
            for (int i = 0; i < 3; ++i)
                #pragma unroll
                for (int j = 0; j < 4; ++j) {
                    acc[i][j] += w4[i].x * x4[j].x;
                    acc[i][j] += w4[i].y * x4[j].y;
                    acc[i][j] += w4[i].z * x4[j].z;
                    acc[i][j] += w4[i].w * x4[j].w;
                }
        }
        #pragma unroll
        for (int j = 0; j < 4; ++j) {
            const int rr = rt + 16 * j;
            if (rr < m) {
                const size_t rbase =
                    (size_t)rl[rr] * (KC2 * NC_N) + (size_t)kc * NC_N;
                #pragma unroll
                for (int i = 0; i < 3; ++i)
                    part2[rbase + jt + 16 * i] = acc[i][j];
            }
        }
    }
}

__global__ __launch_bounds__(256)
void hc_child_reduce(const float* __restrict__ part2, const float* __restrict__ b0,
                     const float* __restrict__ b1, const int* __restrict__ pclass,
                     float* __restrict__ out_c0, float* __restrict__ out_c1) {
    const int t = blockIdx.x * 256 + threadIdx.x;
    const int row = t / NC_N;
    const int j = t - row * NC_N;
    const float* prow = &part2[(size_t)row * (KC2 * NC_N)];
    float lv[KC2];
    #pragma unroll
    for (int kc = 0; kc < KC2; ++kc) lv[kc] = prow[kc * NC_N + j];
    float v = 0.f;
    #pragma unroll
    for (int kc = 0; kc < KC2; ++kc) v += lv[kc];
    const int c = pclass[row];
    if (j < C0_N)
        out_c0[(size_t)row * C0_N + j] = v + b0[c * C0_N + j];
    else
        out_c1[(size_t)row * C1_N + (j - C0_N)] = v + b1[c * C1_N + (j - C0_N)];
}

// ---------------------------------------------------------------------------
extern "C" void kernel_launch(void* const* d_in, const int* in_sizes, int n_in,
                              void* d_out, int out_size, void* d_ws, size_t ws_size,
                              hipStream_t stream) {
    const float* x  = (const float*)d_in[0];
    const float* pw = (const float*)d_in[1];
    const float* pb = (const float*)d_in[2];
    const float* w0 = (const float*)d_in[3];
    const float* b0 = (const float*)d_in[4];
    const float* w1 = (const float*)d_in[5];
    const float* b1 = (const float*)d_in[6];

    float* out_logits = (float*)d_out;                       // [4096][64]
    float* out_c0     = out_logits + (size_t)B_N * P_N;      // [4096][16]
    float* out_c1     = out_c0     + (size_t)B_N * C0_N;     // [4096][32]

    // ws layout (16B-aligned partials): ints then float regions.
    int*   counts   = (int*)d_ws;              // 64
    int*   nsus     = counts + P_N;            // 1 (+63 pad)
    int*   suspects = counts + 128;            // 4096 (fallback only)
    int*   pclass   = suspects + B_N;          // 4096
    int*   lists    = pclass + B_N;            // 64*4096
    float* partials = (float*)(lists + P_N * B_N);
    // fused: partials = 8*4096*64 f (8MB), part2 after it (6.3MB). ~15.8MB.
    // fallback: partials = 16*4096*64 f (16MB), part2 aliases it. ~17.9MB.
    float* part2f   = partials + (size_t)FKC * B_N * P_N;

    void* kargs[] = { (void*)&x, (void*)&pw, (void*)&pb, (void*)&w0,
                      (void*)&b0, (void*)&w1, (void*)&b1,
                      (void*)&out_logits, (void*)&out_c0, (void*)&out_c1,
                      (void*)&counts, (void*)&pclass, (void*)&lists,
                      (void*)&partials, (void*)&part2f };

    hipError_t err = hipLaunchCooperativeKernel(
        (const void*)hc_fused, dim3(FGRID), dim3(256), kargs, 0, stream);

    if (err != hipSuccess) {
        (void)hipGetLastError();   // clear sticky error; use proven 5-kernel path
        hc_parent_partial<<<dim3(B_N / 64, KC1), 256, 0, stream>>>(
            x, pw, partials, counts, nsus);
        hc_parent_route<<<B_N / 4, 256, 0, stream>>>(
            partials, pb, out_logits, counts, lists, nsus, suspects, pclass);
        hc_fixup<<<64, 256, 0, stream>>>(
            x, pw, pb, nsus, suspects, counts, lists, pclass);
        hc_child_partial<<<dim3(P_N, KC2), 256, 0, stream>>>(
            x, w0, w1, counts, lists, partials);
        hc_child_reduce<<<(B_N * NC_N) / 256, 256, 0, stream>>>(
            partials, b0, b1, pclass, out_c0, out_c1);
    }
}

// Round 11
// 307.410 us; speedup vs baseline: 1.1983x; 1.1983x over previous
//
#include <hip/hip_runtime.h>
#include <hip/hip_bf16.h>

// Sizes fixed by the reference problem.
#define B_N   4096
#define D_N   1024
#define P_N   64
#define C0_N  16
#define C1_N  32
#define NC_N  48    // C0 + C1 concatenated

// parent GEMM K-split
#define KC1   16
#define DKC1  64
#define L1S   68     // 64+4: 16B-aligned rows; rows 16 apart -> 2-way bank alias (free)

// child GEMM K-split
#define KC2   8
#define DKC2  128
#define L2S   132    // 128+4: same bank math

// Tie physics: fp32 softmax probs can only tie when the true logit gap is
// <~2e-7 (exp ulp 6e-8 near 1.0; prob ulp 1.9e-9 x s~64 = 1.2e-7; exp
// rounding +-6e-8). Our fp32 gap estimate is accurate to ~1e-9. tau=1e-6
// gives 5x margin and flags only ~15-30 rows total.
#define GAP_TAU 1e-6f
#define NEG_INF (-3.402823466e38f)

// ===========================================================================
// K1: parent partial GEMM + ticket-gated reduce/route/fixup.
// Grid 1024 = 64 row-tiles x 16 K-chunks; 256 threads; 4 blocks/CU.
// Each block: register-tiled partial GEMM (r9's proven body, 2 B/FMA),
// partials [row][kc][p] (row block = 4KB contiguous). Then release-fence +
// ticket; the 16th finisher of a row-tile acquires and reduces its 64 rows
// (partials are L2/L3-hot), does top-2 routing, and runs the 4-wave f64
// softmax-emulation fixup for any near-tie rows in the tile.
// No grid barrier anywhere (r10: 3x grid.sync cost ~300us).
// ===========================================================================
__global__ __launch_bounds__(256, 4)
void hc_parent(const float* __restrict__ x,
               const float* __restrict__ pw,
               const float* __restrict__ pb,
               float* __restrict__ out_logits,
               float* __restrict__ partials,
               int* __restrict__ counts,
               int* __restrict__ lists,
               int* __restrict__ tick1) {
    __shared__ float  xs[64 * L1S];
    __shared__ float  ws[64 * L1S];
    __shared__ int    sq[64];
    __shared__ int    sqn;
    __shared__ int    islast;
    __shared__ double ld[P_N];

    const int tid  = threadIdx.x;
    const int tile = blockIdx.x >> 4;    // 0..63
    const int kc   = blockIdx.x & 15;    // 0..15
    const int r0   = tile * 64;
    const int d0   = kc * DKC1;

    // ---- partial GEMM (identical math to r9's hc_parent_partial) ----
    #pragma unroll
    for (int k = 0; k < 4; ++k) {        // x: 64 rows x 64 floats
        const int f = tid + 256 * k, r = f >> 4, dp = (f & 15) * 4;
        *(float4*)&xs[r * L1S + dp] =
            *(const float4*)&x[(size_t)(r0 + r) * D_N + d0 + dp];
    }
    #pragma unroll
    for (int k = 0; k < 4; ++k) {        // pw chunk: 64 rows x 64 floats
        const int f = tid + 256 * k, r = f >> 4, dp = (f & 15) * 4;
        *(float4*)&ws[r * L1S + dp] =
            *(const float4*)&pw[(size_t)r * D_N + d0 + dp];
    }
    __syncthreads();

    {
        const int pt = tid & 15;
        const int rt = tid >> 4;
        float acc[4][4] = {};            // [i: parent][j: row]
        #pragma unroll
        for (int d = 0; d < DKC1; d += 4) {
            float4 w4[4], x4[4];
            #pragma unroll
            for (int i = 0; i < 4; ++i)
                w4[i] = *(const float4*)&ws[(pt + 16 * i) * L1S + d];
            #pragma unroll
            for (int j = 0; j < 4; ++j)
                x4[j] = *(const float4*)&xs[(rt + 16 * j) * L1S + d];
            #pragma unroll
            for (int i = 0; i < 4; ++i)
                #pragma unroll
                for (int j = 0; j < 4; ++j) {
                    acc[i][j] += w4[i].x * x4[j].x;
                    acc[i][j] += w4[i].y * x4[j].y;
                    acc[i][j] += w4[i].z * x4[j].z;
                    acc[i][j] += w4[i].w * x4[j].w;
                }
        }
        #pragma unroll
        for (int j = 0; j < 4; ++j) {
            const size_t rbase =
                (size_t)(r0 + rt + 16 * j) * (KC1 * P_N) + (size_t)kc * P_N;
            #pragma unroll
            for (int i = 0; i < 4; ++i)
                partials[rbase + pt + 16 * i] = acc[i][j];
        }
    }

    // ---- ticket: last finisher of this row-tile reduces & routes ----
    __threadfence();                      // release my partial writes
    if (tid == 0) {
        islast = (atomicAdd(&tick1[tile], 1) == KC1 - 1);
        sqn = 0;
    }
    __syncthreads();
    if (!islast) return;
    __threadfence();                      // acquire others' partials

    const int p = tid & 63;
    const int w = tid >> 6;               // wave 0..3

    #pragma unroll 2
    for (int rr = w * 16; rr < w * 16 + 16; ++rr) {
        const int row = r0 + rr;
        const float* prow = &partials[(size_t)row * (KC1 * P_N)];
        float lv[KC1];
        #pragma unroll
        for (int k2 = 0; k2 < KC1; ++k2)
            lv[k2] = prow[k2 * P_N + p];
        float l = pb[p];
        #pragma unroll
        for (int k2 = 0; k2 < KC1; ++k2)
            l += lv[k2];

        out_logits[(size_t)row * P_N + p] = l;

        // top-2 across the wave (lanes == parents), first-max tiebreak
        float m1 = l;
        int   i1 = p;
        float m2 = NEG_INF;
        #pragma unroll
        for (int off = 32; off > 0; off >>= 1) {
            const float om1 = __shfl_xor(m1, off);
            const int   oi1 = __shfl_xor(i1, off);
            const float om2 = __shfl_xor(m2, off);
            if (om1 > m1 || (om1 == m1 && oi1 < i1)) {
                m2 = fmaxf(m1, om2);
                m1 = om1;
                i1 = oi1;
            } else {
                m2 = fmaxf(m2, om1);
            }
        }
        if (p == 0) {
            if (m1 - m2 > GAP_TAU) {
                const int pos = atomicAdd(&counts[i1], 1);
                lists[i1 * B_N + pos] = row;
            } else {
                const int q = atomicAdd(&sqn, 1);
                sq[q] = row;
            }
        }
    }
    __syncthreads();

    // ---- inline fixup: emulate the reference's fp32 softmax in f64 ----
    // (exp quantization near 1.0 ties near-equal logits; argmax takes the
    // FIRST tied index). 4 waves cooperate: wave w computes parents
    // [w*16, w*16+16) via full-wave coalesced dots.
    const int nq = sqn;
    for (int qi = 0; qi < nq; ++qi) {
        const int row = sq[qi];
        const float* xr = &x[(size_t)row * D_N + p * 16];
        float4 xv[4];
        #pragma unroll
        for (int k = 0; k < 4; ++k)
            xv[k] = *(const float4*)&xr[k * 4];

        #pragma unroll 2
        for (int pass = 0; pass < 16; ++pass) {
            const int pp = w * 16 + pass;
            const float* wr = &pw[(size_t)pp * D_N + p * 16];
            double a0 = 0.0, a1 = 0.0, a2 = 0.0, a3 = 0.0;
            #pragma unroll
            for (int k = 0; k < 4; ++k) {
                const float4 wv = *(const float4*)&wr[k * 4];
                a0 = fma((double)wv.x, (double)xv[k].x, a0);
                a1 = fma((double)wv.y, (double)xv[k].y, a1);
                a2 = fma((double)wv.z, (double)xv[k].z, a2);
                a3 = fma((double)wv.w, (double)xv[k].w, a3);
            }
            double a = (a0 + a1) + (a2 + a3);
            #pragma unroll
            for (int off = 32; off > 0; off >>= 1)
                a += __shfl_xor(a, off);
            if (p == 0) ld[pp] = a;
        }
        __syncthreads();

        if (w == 0) {
            const double accv = (double)pb[p] + ld[p];
            const float  l32  = (float)accv;
            float m = l32;
            #pragma unroll
            for (int off = 32; off > 0; off >>= 1)
                m = fmaxf(m, __shfl_xor(m, off));
            const float e = (float)exp((double)(l32 - m));  // correctly-rounded
            double es = (double)e;
            #pragma unroll
            for (int off = 32; off > 0; off >>= 1)
                es += __shfl_xor(es, off);
            es = __shfl(es, 0);
            const float s    = (float)es;
            const float prob = e / s;     // IEEE f32 divide: ties survive
            float pm = prob;
            int   pi = p;
            #pragma unroll
            for (int off = 32; off > 0; off >>= 1) {
                const float opm = __shfl_xor(pm, off);
                const int   opi = __shfl_xor(pi, off);
                if (opm > pm || (opm == pm && opi < pi)) { pm = opm; pi = opi; }
            }
            if (p == 0) {
                const int pos = atomicAdd(&counts[pi], 1);
                lists[pi * B_N + pos] = row;
            }
        }
        __syncthreads();
    }
}

// ===========================================================================
// K2: child partial GEMM + ticket-gated class reduce.
// Grid 512 = 64 classes x 8 K-chunks; weights staged once per block; loop
// over 64-row gathered tiles. part2 [row][kc][j]. The 8th finisher of a
// class reduces all its rows (+bias, class-local) straight to c0/c1.
// ===========================================================================
__global__ __launch_bounds__(256, 2)
void hc_child(const float* __restrict__ x,
              const float* __restrict__ w0,
              const float* __restrict__ w1,
              const float* __restrict__ b0,
              const float* __restrict__ b1,
              const int* __restrict__ counts,
              const int* __restrict__ lists,
              float* __restrict__ part2,
              float* __restrict__ out_c0,
              float* __restrict__ out_c1,
              int* __restrict__ tick2) {
    __shared__ int   rl[64];
    __shared__ float xs[64 * L2S];
    __shared__ float ws[NC_N * L2S];
    __shared__ int   islast;

    const int tid = threadIdx.x;
    const int c   = blockIdx.x >> 3;     // 0..63
    const int kc  = blockIdx.x & 7;      // 0..7
    const int n   = counts[c];
    const int d0  = kc * DKC2;

    // stage class's 48 child-weight rows once: 1536 float4, 6 per thread
    #pragma unroll
    for (int k = 0; k < 6; ++k) {
        const int f = tid + 256 * k, j = f >> 5, dp = (f & 31) * 4;
        const float* src = (j < C0_N)
            ? &w0[((size_t)c * C0_N + j) * D_N + d0 + dp]
            : &w1[((size_t)c * C1_N + (j - C0_N)) * D_N + d0 + dp];
        *(float4*)&ws[j * L2S + dp] = *(const float4*)src;
    }

    const int jt = tid & 15;
    const int rt = tid >> 4;

    for (int t0 = 0; t0 < n; t0 += 64) {
        const int m = min(64, n - t0);
        __syncthreads();
        if (tid < 64)
            rl[tid] = lists[c * B_N + t0 + (tid < m ? tid : 0)];
        __syncthreads();
        #pragma unroll
        for (int k = 0; k < 8; ++k) {    // gathered x: 64 rows x 128 floats
            const int f = tid + 256 * k, r = f >> 5, dp = (f & 31) * 4;
            *(float4*)&xs[r * L2S + dp] =
                *(const float4*)&x[(size_t)rl[r] * D_N + d0 + dp];
        }
        __syncthreads();

        float acc[3][4] = {};            // [i: output][j: row]
        #pragma unroll 2
        for (int d = 0; d < DKC2; d += 4) {
            float4 w4[3], x4[4];
            #pragma unroll
            for (int i = 0; i < 3; ++i)
                w4[i] = *(const float4*)&ws[(jt + 16 * i) * L2S + d];
            #pragma unroll
            for (int j = 0; j < 4; ++j)
                x4[j] = *(const float4*)&xs[(rt + 16 * j) * L2S + d];
            #pragma unroll
            for (int i = 0; i < 3; ++i)
                #pragma unroll
                for (int j = 0; j < 4; ++j) {
                    acc[i][j] += w4[i].x * x4[j].x;
                    acc[i][j] += w4[i].y * x4[j].y;
                    acc[i][j] += w4[i].z * x4[j].z;
                    acc[i][j] += w4[i].w * x4[j].w;
                }
        }

        #pragma unroll
        for (int j = 0; j < 4; ++j) {
            const int rr = rt + 16 * j;
            if (rr < m) {
                const size_t rbase =
                    (size_t)rl[rr] * (KC2 * NC_N) + (size_t)kc * NC_N;
                #pragma unroll
                for (int i = 0; i < 3; ++i)
                    part2[rbase + jt + 16 * i] = acc[i][j];
            }
        }
    }

    // ---- ticket: last finisher of this class reduces to outputs ----
    __threadfence();
    if (tid == 0)
        islast = (atomicAdd(&tick2[c], 1) == KC2 - 1);
    __syncthreads();
    if (!islast) return;
    __threadfence();

    for (int idx = tid; idx < n * NC_N; idx += 256) {
        const int rr  = idx / NC_N;
        const int j   = idx - rr * NC_N;
        const int row = lists[c * B_N + rr];
        const float* prow = &part2[(size_t)row * (KC2 * NC_N)];
        float lv[KC2];
        #pragma unroll
        for (int k2 = 0; k2 < KC2; ++k2)
            lv[k2] = prow[k2 * NC_N + j];
        float v = 0.f;
        #pragma unroll
        for (int k2 = 0; k2 < KC2; ++k2)
            v += lv[k2];
        if (j < C0_N)
            out_c0[(size_t)row * C0_N + j] = v + b0[c * C0_N + j];
        else
            out_c1[(size_t)row * C1_N + (j - C0_N)] =
                v + b1[c * C1_N + (j - C0_N)];
    }
}

// ---------------------------------------------------------------------------
extern "C" void kernel_launch(void* const* d_in, const int* in_sizes, int n_in,
                              void* d_out, int out_size, void* d_ws, size_t ws_size,
                              hipStream_t stream) {
    const float* x  = (const float*)d_in[0];
    const float* pw = (const float*)d_in[1];
    const float* pb = (const float*)d_in[2];
    const float* w0 = (const float*)d_in[3];
    const float* b0 = (const float*)d_in[4];
    const float* w1 = (const float*)d_in[5];
    const float* b1 = (const float*)d_in[6];

    float* out_logits = (float*)d_out;                       // [4096][64]
    float* out_c0     = out_logits + (size_t)B_N * P_N;      // [4096][16]
    float* out_c1     = out_c0     + (size_t)B_N * C0_N;     // [4096][32]

    // ws: [counts 64 | tick1 64 | tick2 64 | pad to 256] [lists 64*4096]
    //     [partials 16MB, aliased by part2 6MB]
    int*   counts   = (int*)d_ws;
    int*   tick1    = counts + 64;
    int*   tick2    = tick1 + 64;
    int*   lists    = counts + 256;
    float* partials = (float*)(lists + P_N * B_N);
    float* part2    = partials;          // K1's partials fully consumed in K1

    hipMemsetAsync(counts, 0, 192 * sizeof(int), stream);

    hc_parent<<<64 * KC1, 256, 0, stream>>>(
        x, pw, pb, out_logits, partials, counts, lists, tick1);

    hc_child<<<P_N * KC2, 256, 0, stream>>>(
        x, w0, w1, b0, b1, counts, lists, part2, out_c0, out_c1, tick2);
}

// Round 12
// 110.500 us; speedup vs baseline: 3.3338x; 2.7820x over previous
//
#include <hip/hip_runtime.h>
#include <hip/hip_bf16.h>

// Sizes fixed by the reference problem.
#define B_N   4096
#define D_N   1024
#define P_N   64
#define C0_N  16
#define C1_N  32
#define NC_N  48    // C0 + C1 concatenated

// parent GEMM K-split
#define KC1   16
#define DKC1  64
#define L1S   68     // 64+4: 16B-aligned rows; rows 16 apart -> 2-way bank alias (free)

// child GEMM K-split (in-block loop, no partials)
#define KC2   8
#define DKC2  128
#define L2S   132    // 128+4: same bank math

#define SEG   768    // child row-list segment capacity (class n ~ 64 +/- 24)

// Tie physics: fp32 softmax probs can only tie when the true logit gap is
// <~2e-7 (exp ulp 6e-8 near 1.0; prob ulp 1.9e-9 x s~64 = 1.2e-7; exp
// rounding +-6e-8). Our fp32 gap estimate is accurate to ~1e-9. tau=1e-6
// gives 5x margin and flags only ~15-30 rows total.
#define GAP_TAU 1e-6f
#define NEG_INF (-3.402823466e38f)

// NOTE (r10/r11 lesson): NO device-scope fences or grid barriers anywhere.
// grid.sync ~100us each (r10); per-block __threadfence = L2 writeback storm,
// +180us (r11). All cross-block hand-off is via kernel boundaries.

// ===========================================================================
// A: parent-logit partials (r9's proven kernel). Grid (64 tiles, 16 kc),
// 1024 blocks, 4/CU. Partials [row][kc][p] (row block 4KB contiguous).
// Block (0,0) zeroes nsus.
// ===========================================================================
__global__ __launch_bounds__(256, 4)
void hc_parent_partial(const float* __restrict__ x,
                       const float* __restrict__ pw,
                       float* __restrict__ partials,
                       int* __restrict__ nsus) {
    __shared__ float xs[64 * L1S];
    __shared__ float ws[P_N * L1S];
    const int tid = threadIdx.x;
    if (blockIdx.x == 0 && blockIdx.y == 0 && tid == 0) *nsus = 0;

    const int r0 = blockIdx.x * 64;
    const int d0 = blockIdx.y * DKC1;

    #pragma unroll
    for (int k = 0; k < 4; ++k) {        // x: 64 rows x 64 floats
        const int f = tid + 256 * k, r = f >> 4, dp = (f & 15) * 4;
        *(float4*)&xs[r * L1S + dp] =
            *(const float4*)&x[(size_t)(r0 + r) * D_N + d0 + dp];
    }
    #pragma unroll
    for (int k = 0; k < 4; ++k) {        // pw chunk: 64 rows x 64 floats
        const int f = tid + 256 * k, r = f >> 4, dp = (f & 15) * 4;
        *(float4*)&ws[r * L1S + dp] =
            *(const float4*)&pw[(size_t)r * D_N + d0 + dp];
    }
    __syncthreads();

    const int pt = tid & 15;
    const int rt = tid >> 4;
    float acc[4][4] = {};                // [i: parent][j: row]
    #pragma unroll
    for (int d = 0; d < DKC1; d += 4) {
        float4 w4[4], x4[4];
        #pragma unroll
        for (int i = 0; i < 4; ++i)
            w4[i] = *(const float4*)&ws[(pt + 16 * i) * L1S + d];
        #pragma unroll
        for (int j = 0; j < 4; ++j)
            x4[j] = *(const float4*)&xs[(rt + 16 * j) * L1S + d];
        #pragma unroll
        for (int i = 0; i < 4; ++i)
            #pragma unroll
            for (int j = 0; j < 4; ++j) {
                acc[i][j] += w4[i].x * x4[j].x;
                acc[i][j] += w4[i].y * x4[j].y;
                acc[i][j] += w4[i].z * x4[j].z;
                acc[i][j] += w4[i].w * x4[j].w;
            }
    }
    const int kcb = blockIdx.y;
    #pragma unroll
    for (int j = 0; j < 4; ++j) {
        const size_t rbase =
            (size_t)(r0 + rt + 16 * j) * (KC1 * P_N) + (size_t)kcb * P_N;
        #pragma unroll
        for (int i = 0; i < 4; ++i)
            partials[rbase + pt + 16 * i] = acc[i][j];
    }
}

// ===========================================================================
// B1: fast route (r9's proven kernel, minus atomic binning). Reduce + bias
// -> logits; wave top-2; pclass[row] = argmax if gap > tau, else append to
// suspect list for B2. Wave = one row; block = 4 rows; grid = 1024.
// ===========================================================================
__global__ __launch_bounds__(256)
void hc_parent_route(const float* __restrict__ partials,
                     const float* __restrict__ pb,
                     float* __restrict__ out_logits,
                     int* __restrict__ nsus,
                     int* __restrict__ suspects,
                     int* __restrict__ pclass) {
    const int tid = threadIdx.x;
    const int p = tid & 63, w = tid >> 6;
    const int row = blockIdx.x * 4 + w;

    const float* prow = &partials[(size_t)row * (KC1 * P_N)];
    float lv[KC1];
    #pragma unroll
    for (int kc = 0; kc < KC1; ++kc) lv[kc] = prow[kc * P_N + p];
    float l = pb[p];
    #pragma unroll
    for (int kc = 0; kc < KC1; ++kc) l += lv[kc];

    out_logits[(size_t)row * P_N + p] = l;

    // top-2 across the wave (lanes == parents), first-max tiebreak
    float m1 = l; int i1 = p; float m2 = NEG_INF;
    #pragma unroll
    for (int off = 32; off > 0; off >>= 1) {
        const float om1 = __shfl_xor(m1, off);
        const int   oi1 = __shfl_xor(i1, off);
        const float om2 = __shfl_xor(m2, off);
        if (om1 > m1 || (om1 == m1 && oi1 < i1)) {
            m2 = fmaxf(m1, om2); m1 = om1; i1 = oi1;
        } else m2 = fmaxf(m2, om1);
    }
    if (p == 0) {
        if (m1 - m2 > GAP_TAU) {
            pclass[row] = i1;
        } else {
            const int pos = atomicAdd(nsus, 1);
            suspects[pos] = row;
        }
    }
}

// ===========================================================================
// B2: suspect fixup (r9's proven kernel; writes pclass only). One block
// (4 waves) per suspect row; emulates the reference's fp32 softmax in f64
// (exp quantization near 1.0 ties near-equal logits; argmax takes the FIRST
// tied index). Grid = 64 blocks, grid-stride over ~26 suspects.
// ===========================================================================
__global__ __launch_bounds__(256)
void hc_fixup(const float* __restrict__ x, const float* __restrict__ pw,
              const float* __restrict__ pb, const int* __restrict__ nsus,
              const int* __restrict__ suspects, int* __restrict__ pclass) {
    __shared__ double ld[P_N];
    const int tid = threadIdx.x, lane = tid & 63, w = tid >> 6;
    const int ns = *nsus;
    for (int sidx = blockIdx.x; sidx < ns; sidx += gridDim.x) {
        const int row = suspects[sidx];
        __syncthreads();
        const float* xr = &x[(size_t)row * D_N + lane * 16];
        float4 xv[4];
        #pragma unroll
        for (int k = 0; k < 4; ++k) xv[k] = *(const float4*)&xr[k * 4];
        #pragma unroll 2
        for (int pass = 0; pass < 16; ++pass) {
            const int pp = w * 16 + pass;
            const float* wr = &pw[(size_t)pp * D_N + lane * 16];
            double a0 = 0.0, a1 = 0.0, a2 = 0.0, a3 = 0.0;
            #pragma unroll
            for (int k = 0; k < 4; ++k) {
                const float4 wv = *(const float4*)&wr[k * 4];
                a0 = fma((double)wv.x, (double)xv[k].x, a0);
                a1 = fma((double)wv.y, (double)xv[k].y, a1);
                a2 = fma((double)wv.z, (double)xv[k].z, a2);
                a3 = fma((double)wv.w, (double)xv[k].w, a3);
            }
            double a = (a0 + a1) + (a2 + a3);
            #pragma unroll
            for (int off = 32; off > 0; off >>= 1) a += __shfl_xor(a, off);
            if (lane == 0) ld[pp] = a;
        }
        __syncthreads();
        if (w == 0) {
            const double acc = (double)pb[lane] + ld[lane];
            const float l32 = (float)acc;
            float m = l32;
            #pragma unroll
            for (int off = 32; off > 0; off >>= 1)
                m = fmaxf(m, __shfl_xor(m, off));
            const float e = (float)exp((double)(l32 - m));
            double es = (double)e;
            #pragma unroll
            for (int off = 32; off > 0; off >>= 1) es += __shfl_xor(es, off);
            es = __shfl(es, 0);
            const float s = (float)es;
            const float prob = e / s;    // IEEE f32 divide: ties survive
            float pm = prob; int pi = lane;
            #pragma unroll
            for (int off = 32; off > 0; off >>= 1) {
                const float opm = __shfl_xor(pm, off);
                const int   opi = __shfl_xor(pi, off);
                if (opm > pm || (opm == pm && opi < pi)) { pm = opm; pi = opi; }
            }
            if (lane == 0) pclass[row] = pi;
        }
        __syncthreads();
    }
}

// ===========================================================================
// K4: child GEMM, full-K per block, NO partials/reduce/atomics.
// Grid = 64 class-blocks. Each block: (1) scans pclass (16KB), compacts its
// rows via LDS prefix-scan -> row-ascending list (deterministic); (2) for
// each 64-row tile, accumulates acc[3][4] across all 8 K-chunks (stage ws +
// gathered xs per chunk), then writes c0/c1 + bias directly.
// Replaces r9's C (part2 write) + D (reduce) and one launch.
// ===========================================================================
__global__ __launch_bounds__(256, 2)
void hc_child(const float* __restrict__ x,
              const float* __restrict__ w0,
              const float* __restrict__ w1,
              const float* __restrict__ b0,
              const float* __restrict__ b1,
              const int* __restrict__ pclass,
              float* __restrict__ out_c0,
              float* __restrict__ out_c1) {
    __shared__ float xs[64 * L2S];
    __shared__ float ws[NC_N * L2S];
    __shared__ int   slist[SEG];
    __shared__ int   scnt[256];

    const int tid = threadIdx.x;
    const int c   = blockIdx.x;

    // ---- count this thread's 16-row chunk ----
    const int rbase = tid * 16;
    int myc = 0;
    #pragma unroll
    for (int k = 0; k < 16; ++k)
        myc += (pclass[rbase + k] == c) ? 1 : 0;
    scnt[tid] = myc;
    __syncthreads();
    // inclusive Hillis-Steele scan over 256 thread-counts
    for (int off = 1; off < 256; off <<= 1) {
        const int v = scnt[tid];
        const int u = (tid >= off) ? scnt[tid - off] : 0;
        __syncthreads();
        scnt[tid] = v + u;
        __syncthreads();
    }
    const int excl = scnt[tid] - myc;
    const int n    = scnt[255];

    const int jt = tid & 15;
    const int rt = tid >> 4;

    for (int s0 = 0; s0 < n; s0 += SEG) {
        // ---- build ordered segment list (row-ascending, deterministic) ----
        __syncthreads();
        {
            int pos = excl;
            #pragma unroll
            for (int k = 0; k < 16; ++k) {
                const int row = rbase + k;
                if (pclass[row] == c) {
                    const int rel = pos - s0;
                    if (rel >= 0 && rel < SEG) slist[rel] = row;
                    ++pos;
                }
            }
        }
        __syncthreads();
        const int mseg = min(SEG, n - s0);

        for (int t0 = 0; t0 < mseg; t0 += 64) {
            const int m = min(64, mseg - t0);
            float acc[3][4] = {};        // [i: output][j: row]

            for (int kc = 0; kc < KC2; ++kc) {
                const int d0 = kc * DKC2;
                __syncthreads();         // prior compute's LDS reads done
                // stage class's 48 weight rows for this chunk
                #pragma unroll
                for (int k = 0; k < 6; ++k) {
                    const int f = tid + 256 * k, j = f >> 5, dp = (f & 31) * 4;
                    const float* src = (j < C0_N)
                        ? &w0[((size_t)c * C0_N + j) * D_N + d0 + dp]
                        : &w1[((size_t)c * C1_N + (j - C0_N)) * D_N + d0 + dp];
                    *(float4*)&ws[j * L2S + dp] = *(const float4*)src;
                }
                // stage gathered x rows for this chunk
                #pragma unroll
                for (int k = 0; k < 8; ++k) {
                    const int f = tid + 256 * k, r = f >> 5, dp = (f & 31) * 4;
                    const int row = slist[t0 + (r < m ? r : 0)];
                    *(float4*)&xs[r * L2S + dp] =
                        *(const float4*)&x[(size_t)row * D_N + d0 + dp];
                }
                __syncthreads();

                #pragma unroll 2
                for (int d = 0; d < DKC2; d += 4) {
                    float4 w4[3], x4[4];
                    #pragma unroll
                    for (int i = 0; i < 3; ++i)
                        w4[i] = *(const float4*)&ws[(jt + 16 * i) * L2S + d];
                    #pragma unroll
                    for (int j = 0; j < 4; ++j)
                        x4[j] = *(const float4*)&xs[(rt + 16 * j) * L2S + d];
                    #pragma unroll
                    for (int i = 0; i < 3; ++i)
                        #pragma unroll
                        for (int j = 0; j < 4; ++j) {
                            acc[i][j] += w4[i].x * x4[j].x;
                            acc[i][j] += w4[i].y * x4[j].y;
                            acc[i][j] += w4[i].z * x4[j].z;
                            acc[i][j] += w4[i].w * x4[j].w;
                        }
                }
            }

            // ---- write outputs + bias ----
            #pragma unroll
            for (int j = 0; j < 4; ++j) {
                const int rr = rt + 16 * j;
                if (rr < m) {
                    const int row = slist[t0 + rr];
                    #pragma unroll
                    for (int i = 0; i < 3; ++i) {
                        const int jj = jt + 16 * i;
                        if (jj < C0_N)
                            out_c0[(size_t)row * C0_N + jj] =
                                acc[i][j] + b0[c * C0_N + jj];
                        else
                            out_c1[(size_t)row * C1_N + (jj - C0_N)] =
                                acc[i][j] + b1[c * C1_N + (jj - C0_N)];
                    }
                }
            }
        }
    }
}

// ---------------------------------------------------------------------------
extern "C" void kernel_launch(void* const* d_in, const int* in_sizes, int n_in,
                              void* d_out, int out_size, void* d_ws, size_t ws_size,
                              hipStream_t stream) {
    const float* x  = (const float*)d_in[0];
    const float* pw = (const float*)d_in[1];
    const float* pb = (const float*)d_in[2];
    const float* w0 = (const float*)d_in[3];
    const float* b0 = (const float*)d_in[4];
    const float* w1 = (const float*)d_in[5];
    const float* b1 = (const float*)d_in[6];

    float* out_logits = (float*)d_out;                       // [4096][64]
    float* out_c0     = out_logits + (size_t)B_N * P_N;      // [4096][16]
    float* out_c1     = out_c0     + (size_t)B_N * C0_N;     // [4096][32]

    // ws: [nsus 1 (+63 pad)] [suspects 4096] [pclass 4096] [partials 16MB]
    int*   nsus     = (int*)d_ws;
    int*   suspects = nsus + 64;
    int*   pclass   = suspects + B_N;
    float* partials = (float*)(pclass + B_N);   // offset 33,024 B (16B-aligned)

    hc_parent_partial<<<dim3(B_N / 64, KC1), 256, 0, stream>>>(
        x, pw, partials, nsus);

    hc_parent_route<<<B_N / 4, 256, 0, stream>>>(
        partials, pb, out_logits, nsus, suspects, pclass);

    hc_fixup<<<64, 256, 0, stream>>>(
        x, pw, pb, nsus, suspects, pclass);

    hc_child<<<P_N, 256, 0, stream>>>(
        x, w0, w1, b0, b1, pclass, out_c0, out_c1);
}

// Round 13
// 72.096 us; speedup vs baseline: 5.1097x; 1.5327x over previous
//
#include <hip/hip_runtime.h>
#include <hip/hip_bf16.h>

// Sizes fixed by the reference problem.
#define B_N   4096
#define D_N   1024
#define P_N   64
#define C0_N  16
#define C1_N  32
#define NC_N  48    // C0 + C1 concatenated

// parent GEMM K-split
#define KC1   16
#define DKC1  64
#define L1S   68     // 64+4: 16B-aligned rows; rows 16 apart -> 2-way bank alias (free)

// child GEMM K-split
#define KC2   8
#define DKC2  128
#define L2S   132    // 128+4: same bank math

// Tie physics: fp32 softmax probs can only tie when the true logit gap is
// <~2e-7 (exp ulp 6e-8 near 1.0; prob ulp 1.9e-9 x s~64 = 1.2e-7; exp
// rounding +-6e-8). Our fp32 gap estimate is accurate to ~1e-9. tau=1e-6
// gives 5x margin and flags only ~15-30 rows total.
#define GAP_TAU 1e-6f
#define NEG_INF (-3.402823466e38f)

// NOTE (r10/r11/r12 lessons): no grid.sync (~100us each), no per-block
// device fences (L2 writeback storm, +180us), no low-block-count kernels
// (64 blocks = 2% occupancy, 87us). Hand-off at kernel boundaries only;
// every kernel >= ~500 blocks.

// ===========================================================================
// A: parent-logit partials (proven since r9). Grid (64 tiles, 16 kc) = 1024
// blocks, 4/CU. Partials [row][kc][p] (row block 4KB contiguous).
// Block (0,0) zeroes counts.
// ===========================================================================
__global__ __launch_bounds__(256, 4)
void hc_parent_partial(const float* __restrict__ x,
                       const float* __restrict__ pw,
                       float* __restrict__ partials,
                       int* __restrict__ counts) {
    __shared__ float xs[64 * L1S];
    __shared__ float ws[P_N * L1S];
    const int tid = threadIdx.x;
    if (blockIdx.x == 0 && blockIdx.y == 0 && tid < P_N) counts[tid] = 0;

    const int r0 = blockIdx.x * 64;
    const int d0 = blockIdx.y * DKC1;

    #pragma unroll
    for (int k = 0; k < 4; ++k) {        // x: 64 rows x 64 floats
        const int f = tid + 256 * k, r = f >> 4, dp = (f & 15) * 4;
        *(float4*)&xs[r * L1S + dp] =
            *(const float4*)&x[(size_t)(r0 + r) * D_N + d0 + dp];
    }
    #pragma unroll
    for (int k = 0; k < 4; ++k) {        // pw chunk: 64 rows x 64 floats
        const int f = tid + 256 * k, r = f >> 4, dp = (f & 15) * 4;
        *(float4*)&ws[r * L1S + dp] =
            *(const float4*)&pw[(size_t)r * D_N + d0 + dp];
    }
    __syncthreads();

    const int pt = tid & 15;
    const int rt = tid >> 4;
    float acc[4][4] = {};                // [i: parent][j: row]
    #pragma unroll
    for (int d = 0; d < DKC1; d += 4) {
        float4 w4[4], x4[4];
        #pragma unroll
        for (int i = 0; i < 4; ++i)
            w4[i] = *(const float4*)&ws[(pt + 16 * i) * L1S + d];
        #pragma unroll
        for (int j = 0; j < 4; ++j)
            x4[j] = *(const float4*)&xs[(rt + 16 * j) * L1S + d];
        #pragma unroll
        for (int i = 0; i < 4; ++i)
            #pragma unroll
            for (int j = 0; j < 4; ++j) {
                acc[i][j] += w4[i].x * x4[j].x;
                acc[i][j] += w4[i].y * x4[j].y;
                acc[i][j] += w4[i].z * x4[j].z;
                acc[i][j] += w4[i].w * x4[j].w;
            }
    }
    const int kcb = blockIdx.y;
    #pragma unroll
    for (int j = 0; j < 4; ++j) {
        const size_t rbase =
            (size_t)(r0 + rt + 16 * j) * (KC1 * P_N) + (size_t)kcb * P_N;
        #pragma unroll
        for (int i = 0; i < 4; ++i)
            partials[rbase + pt + 16 * i] = acc[i][j];
    }
}

// ===========================================================================
// B: route + block-local cooperative f64 fixup (B1+B2 merged; one launch).
// Block = 4 rows (wave = one row's 64 parents). Fast path: partial reduce
// + bias -> logits, top-2, bin via counts/lists + pclass. Near-ties go to
// an LDS queue; after a barrier, the WHOLE BLOCK (4 waves cooperatively,
// B2's proven structure) recomputes the queued rows' logits in f64 and
// emulates the reference's fp32 softmax (exp quantization near 1.0 ties
// near-equal logits; argmax takes the FIRST tied index). Only ~26 of 1024
// blocks hit the slow path.
// ===========================================================================
__global__ __launch_bounds__(256, 6)
void hc_parent_route(const float* __restrict__ partials,
                     const float* __restrict__ pb,
                     const float* __restrict__ x,
                     const float* __restrict__ pw,
                     float* __restrict__ out_logits,
                     int* __restrict__ counts,
                     int* __restrict__ lists,
                     int* __restrict__ pclass) {
    __shared__ double ld[P_N];
    __shared__ int    sq[8];
    __shared__ int    sqn;

    const int tid = threadIdx.x;
    const int p   = tid & 63;
    const int w   = tid >> 6;
    const int row = blockIdx.x * 4 + w;

    if (tid == 0) sqn = 0;

    // ---- fast path ----
    const float* prow = &partials[(size_t)row * (KC1 * P_N)];
    float lv[KC1];
    #pragma unroll
    for (int kc = 0; kc < KC1; ++kc) lv[kc] = prow[kc * P_N + p];
    float l = pb[p];
    #pragma unroll
    for (int kc = 0; kc < KC1; ++kc) l += lv[kc];

    out_logits[(size_t)row * P_N + p] = l;

    float m1 = l; int i1 = p; float m2 = NEG_INF;
    #pragma unroll
    for (int off = 32; off > 0; off >>= 1) {
        const float om1 = __shfl_xor(m1, off);
        const int   oi1 = __shfl_xor(i1, off);
        const float om2 = __shfl_xor(m2, off);
        if (om1 > m1 || (om1 == m1 && oi1 < i1)) {
            m2 = fmaxf(m1, om2); m1 = om1; i1 = oi1;
        } else m2 = fmaxf(m2, om1);
    }
    if (p == 0) {
        if (m1 - m2 > GAP_TAU) {
            const int pos = atomicAdd(&counts[i1], 1);
            lists[i1 * B_N + pos] = row;
            pclass[row] = i1;
        } else {
            const int q = atomicAdd(&sqn, 1);
            sq[q] = row;
        }
    }
    __syncthreads();

    const int nq = sqn;
    if (nq == 0) return;    // uniform: all threads past the barrier

    // ---- block-cooperative slow path (~26 blocks total take this) ----
    for (int qi = 0; qi < nq; ++qi) {
        const int srow = sq[qi];
        const float* xr = &x[(size_t)srow * D_N + p * 16];
        float4 xv[4];
        #pragma unroll
        for (int k = 0; k < 4; ++k) xv[k] = *(const float4*)&xr[k * 4];

        #pragma unroll 2
        for (int pass = 0; pass < 16; ++pass) {
            const int pp = w * 16 + pass;
            const float* wr = &pw[(size_t)pp * D_N + p * 16];
            double a0 = 0.0, a1 = 0.0, a2 = 0.0, a3 = 0.0;
            #pragma unroll
            for (int k = 0; k < 4; ++k) {
                const float4 wv = *(const float4*)&wr[k * 4];
                a0 = fma((double)wv.x, (double)xv[k].x, a0);
                a1 = fma((double)wv.y, (double)xv[k].y, a1);
                a2 = fma((double)wv.z, (double)xv[k].z, a2);
                a3 = fma((double)wv.w, (double)xv[k].w, a3);
            }
            double a = (a0 + a1) + (a2 + a3);
            #pragma unroll
            for (int off = 32; off > 0; off >>= 1) a += __shfl_xor(a, off);
            if (p == 0) ld[pp] = a;
        }
        __syncthreads();

        if (w == 0) {
            const double accv = (double)pb[p] + ld[p];
            const float  l32  = (float)accv;
            float m = l32;
            #pragma unroll
            for (int off = 32; off > 0; off >>= 1)
                m = fmaxf(m, __shfl_xor(m, off));
            const float e = (float)exp((double)(l32 - m));  // correctly-rounded
            double es = (double)e;
            #pragma unroll
            for (int off = 32; off > 0; off >>= 1) es += __shfl_xor(es, off);
            es = __shfl(es, 0);
            const float s    = (float)es;
            const float prob = e / s;    // IEEE f32 divide: ties survive
            float pm = prob; int pi = p;
            #pragma unroll
            for (int off = 32; off > 0; off >>= 1) {
                const float opm = __shfl_xor(pm, off);
                const int   opi = __shfl_xor(pi, off);
                if (opm > pm || (opm == pm && opi < pi)) { pm = opm; pi = opi; }
            }
            if (p == 0) {
                const int pos = atomicAdd(&counts[pi], 1);
                lists[pi * B_N + pos] = srow;
                pclass[srow] = pi;
            }
        }
        __syncthreads();
    }
}

// ===========================================================================
// C: child-GEMM partials, one 64-row tile per block (no serial tile loop).
// Grid (64 classes, 8 kc, 4 tile-slots) = 2048 dispatched, ~640 active
// (slots past the class's count exit immediately), ~2.5 blocks/CU.
// part2 [row][kc][j] (row block = 384B contiguous for D).
// ===========================================================================
__global__ __launch_bounds__(256, 2)
void hc_child_partial(const float* __restrict__ x,
                      const float* __restrict__ w0,
                      const float* __restrict__ w1,
                      const int* __restrict__ counts,
                      const int* __restrict__ lists,
                      float* __restrict__ part2) {
    const int c  = blockIdx.x;
    const int kc = blockIdx.y;
    const int n  = counts[c];
    const int t0 = blockIdx.z * 64;
    if (t0 >= n) return;
    const int m  = min(64, n - t0);
    const int d0 = kc * DKC2;

    __shared__ int   rl[64];
    __shared__ float xs[64 * L2S];
    __shared__ float ws[NC_N * L2S];

    const int tid = threadIdx.x;
    if (tid < 64)
        rl[tid] = lists[c * B_N + t0 + (tid < m ? tid : 0)];

    // stage class's 48 child-weight rows: 1536 float4, 6 per thread
    #pragma unroll
    for (int k = 0; k < 6; ++k) {
        const int f = tid + 256 * k, j = f >> 5, dp = (f & 31) * 4;
        const float* src = (j < C0_N)
            ? &w0[((size_t)c * C0_N + j) * D_N + d0 + dp]
            : &w1[((size_t)c * C1_N + (j - C0_N)) * D_N + d0 + dp];
        *(float4*)&ws[j * L2S + dp] = *(const float4*)src;
    }
    __syncthreads();   // rl visible
    // stage gathered x rows: 64 x 128 = 2048 float4, 8 per thread
    #pragma unroll
    for (int k = 0; k < 8; ++k) {
        const int f = tid + 256 * k, r = f >> 5, dp = (f & 31) * 4;
        *(float4*)&xs[r * L2S + dp] =
            *(const float4*)&x[(size_t)rl[r] * D_N + d0 + dp];
    }
    __syncthreads();

    const int jt = tid & 15;
    const int rt = tid >> 4;

    float acc[3][4] = {};                // [i: output][j: row]
    #pragma unroll 2
    for (int d = 0; d < DKC2; d += 4) {
        float4 w4[3], x4[4];
        #pragma unroll
        for (int i = 0; i < 3; ++i)
            w4[i] = *(const float4*)&ws[(jt + 16 * i) * L2S + d];
        #pragma unroll
        for (int j = 0; j < 4; ++j)
            x4[j] = *(const float4*)&xs[(rt + 16 * j) * L2S + d];
        #pragma unroll
        for (int i = 0; i < 3; ++i)
            #pragma unroll
            for (int j = 0; j < 4; ++j) {
                acc[i][j] += w4[i].x * x4[j].x;
                acc[i][j] += w4[i].y * x4[j].y;
                acc[i][j] += w4[i].z * x4[j].z;
                acc[i][j] += w4[i].w * x4[j].w;
            }
    }

    #pragma unroll
    for (int j = 0; j < 4; ++j) {
        const int rr = rt + 16 * j;
        if (rr < m) {
            const size_t rbase =
                (size_t)rl[rr] * (KC2 * NC_N) + (size_t)kc * NC_N;
            #pragma unroll
            for (int i = 0; i < 3; ++i)
                part2[rbase + jt + 16 * i] = acc[i][j];
        }
    }
}

// ===========================================================================
// D: deterministic child partial-sum + bias -> c0/c1. Thread = one (row,j);
// a row's 8 planes are contiguous (384B). Grid = 768 blocks.
// ===========================================================================
__global__ __launch_bounds__(256)
void hc_child_reduce(const float* __restrict__ part2,
                     const float* __restrict__ b0,
                     const float* __restrict__ b1,
                     const int* __restrict__ pclass,
                     float* __restrict__ out_c0,
                     float* __restrict__ out_c1) {
    const int t   = blockIdx.x * 256 + threadIdx.x;   // 0 .. 4096*48-1
    const int row = t / NC_N;
    const int j   = t - row * NC_N;

    const float* prow = &part2[(size_t)row * (KC2 * NC_N)];
    float lv[KC2];
    #pragma unroll
    for (int kc = 0; kc < KC2; ++kc) lv[kc] = prow[kc * NC_N + j];
    float v = 0.f;
    #pragma unroll
    for (int kc = 0; kc < KC2; ++kc) v += lv[kc];

    const int c = pclass[row];
    if (j < C0_N)
        out_c0[(size_t)row * C0_N + j] = v + b0[c * C0_N + j];
    else
        out_c1[(size_t)row * C1_N + (j - C0_N)] = v + b1[c * C1_N + (j - C0_N)];
}

// ---------------------------------------------------------------------------
extern "C" void kernel_launch(void* const* d_in, const int* in_sizes, int n_in,
                              void* d_out, int out_size, void* d_ws, size_t ws_size,
                              hipStream_t stream) {
    const float* x  = (const float*)d_in[0];
    const float* pw = (const float*)d_in[1];
    const float* pb = (const float*)d_in[2];
    const float* w0 = (const float*)d_in[3];
    const float* b0 = (const float*)d_in[4];
    const float* w1 = (const float*)d_in[5];
    const float* b1 = (const float*)d_in[6];

    float* out_logits = (float*)d_out;                       // [4096][64]
    float* out_c0     = out_logits + (size_t)B_N * P_N;      // [4096][16]
    float* out_c1     = out_c0     + (size_t)B_N * C0_N;     // [4096][32]

    // ws: [counts 64] [pclass 4096] [lists 64*4096] [partials 16MB,
    // aliased by part2 6.3MB — partials fully consumed by B before C runs]
    int*   counts   = (int*)d_ws;
    int*   pclass   = counts + P_N;
    int*   lists    = pclass + B_N;
    float* partials = (float*)(lists + P_N * B_N);
    float* part2    = partials;

    hc_parent_partial<<<dim3(B_N / 64, KC1), 256, 0, stream>>>(
        x, pw, partials, counts);

    hc_parent_route<<<B_N / 4, 256, 0, stream>>>(
        partials, pb, x, pw, out_logits, counts, lists, pclass);

    hc_child_partial<<<dim3(P_N, KC2, 4), 256, 0, stream>>>(
        x, w0, w1, counts, lists, part2);

    hc_child_reduce<<<(B_N * NC_N) / 256, 256, 0, stream>>>(
        part2, b0, b1, pclass, out_c0, out_c1);
}